// Round 9
// baseline (195.521 us; speedup 1.0000x reference)
//
#include <hip/hip_runtime.h>

typedef unsigned short u16;
typedef unsigned int u32;
typedef unsigned long long u64;

typedef __bf16 bf16x8 __attribute__((ext_vector_type(8)));
typedef float f32x4 __attribute__((ext_vector_type(4)));

#define OUT_F 4096
#define IN_F 4096
#define M_ROWS 4096              // 2 * 2048
#define NUM_GROUPS ((OUT_F * IN_F) / 32)   // 524288

#define TILE_A_E (256 * 64)      // u16 elements per A LDS buffer (32 KB)

// ---------- helpers ----------

__device__ __forceinline__ u16 f2bf(float f) {
    union { float f; u32 u; } c; c.f = f;
    u32 u = c.u;
    u += 0x7fffu + ((u >> 16) & 1u);   // round-to-nearest-even (finite inputs)
    return (u16)(u >> 16);
}

__device__ __forceinline__ u32 pk2(float a, float b) {
    return (u32)f2bf(a) | ((u32)f2bf(b) << 16);
}

// async global -> LDS, 16 bytes per lane (global_load_lds_dwordx4)
__device__ __forceinline__ void async_copy16(const u16* g, u16* l) {
    __builtin_amdgcn_global_load_lds(
        (const __attribute__((address_space(1))) u32*)g,
        (__attribute__((address_space(3))) u32*)l,
        16, 0, 0);
}

// 32-bit LDS byte address for inline-asm ds_read
__device__ __forceinline__ u32 lds_addr(const u16* p) {
    return (u32)(uintptr_t)(const __attribute__((address_space(3))) u16*)p;
}

// ---------- fused prep (unchanged — HBM-floor, not the bottleneck) ----------
__global__ __launch_bounds__(256) void prep_kernel(
        const float* __restrict__ x, const int* __restrict__ q,
        const float* __restrict__ scales,
        u16* __restrict__ W, u16* __restrict__ Xb) {
    int bid = blockIdx.x;
    int tid = threadIdx.x;
    if (bid < 8192) {
        int t = bid * 256 + tid;                 // [0, NUM_TRIPLETS)
        int b0 = q[3 * t];
        int b1 = q[3 * t + 1];
        int b2 = q[3 * t + 2];
        float mv = scales[t >> 2];
        float s = mv * (2.0f / 7.0f);            // w = v*s - mv
        float o = -mv;

        int v0 = b0 & 7;
        int v1 = (b0 >> 3) & 7;
        int v2 = ((b0 >> 6) & 3) | ((b1 & 1) << 2);
        int v3 = (b1 >> 1) & 7;
        int v4 = (b1 >> 4) & 7;
        int v5 = ((b1 >> 7) & 1) | ((b2 & 3) << 1);
        int v6 = (b2 >> 2) & 7;
        int v7 = (b2 >> 5) & 7;
        uint4 w;
        w.x = pk2(fmaf((float)v0, s, o), fmaf((float)v1, s, o));
        w.y = pk2(fmaf((float)v2, s, o), fmaf((float)v3, s, o));
        w.z = pk2(fmaf((float)v4, s, o), fmaf((float)v5, s, o));
        w.w = pk2(fmaf((float)v6, s, o), fmaf((float)v7, s, o));
        ((uint4*)W)[t] = w;
    } else {
        int i = (bid - 8192) * 256 + tid;
        const float4* p = (const float4*)x + (size_t)i * 2;
        float4 u = p[0], v = p[1];
        uint4 w;
        w.x = pk2(u.x, u.y);
        w.y = pk2(u.z, u.w);
        w.z = pk2(v.x, v.y);
        w.w = pk2(v.z, v.w);
        ((uint4*)Xb)[i] = w;
    }
}

// ---------- 256x128 tile: A via LDS (dbuf), B DIRECT FROM GLOBAL ----------
// C[m][n] = sum_k A[m][k]*B[n][k] + bias[n]
//
// R2..R8 post-mortem: six schedule variants all ~4375 cyc/CU-tile-pair ~=
// LDS-port (2800) and MFMA (2483) mostly in SERIES; overlap won't come.
// R9 cuts LDS-port demand below the MFMA floor instead: B-fragments are
// loaded straight from W (global) into registers — per-lane addresses form
// 64B-contiguous row segments, B-panel is L2/L3-resident (1 MB, reread 16x),
// and the traffic rides the VMEM pipe, not the LDS port. sB is gone; A
// double-buffers in 64 KB -> still 2 blocks/CU; ONE barrier per tile.
//   tile t (vmcnt ledger, audited):
//     entry: 8 outstanding = B(t) loads (issued mid-tile t-1)
//     issue A-DMA(t+1)->buf^1 (8)            [16 outstanding]
//     issue av rows0-3 (8 ds_read)
//     MCOL ladder: vmcnt(14/12/10/8)+lgkm(0) — B(t) pairs drain in order
//     issue av rows4-7; MROW ladder lgkm(6/4/2/0)   [bv(t) last use]
//     issue B(t+1) (8)                        [16 outstanding]
//     vmcnt(8)  -> A-DMA(t+1) complete, B(t+1) stays in flight
//     s_barrier -> next tile reads buf^1 (WAR: this tile's reads lgkm-done)
__global__ __launch_bounds__(256, 2) void gemm_bt_kernel(
        const u16* __restrict__ A, const u16* __restrict__ B,
        const float* __restrict__ bias, float* __restrict__ C) {
    __shared__ u16 sA[2 * TILE_A_E];   // 64 KB

    const int tid = threadIdx.x;
    const int lane = tid & 63;
    const int w = tid >> 6;          // wave 0..3
    const int wr = w >> 1;           // wave row 0..1 (rows wr*128 + [0,128))
    const int wc = w & 1;            // wave col 0..1 (cols wc*64 + [0,64))
    const int ln = lane & 15;
    const int quad = lane >> 4;
    const int lnx = ln & 7;

    // XCD-aware bijective swizzle: 512 blocks, 8 XCDs, 64 contiguous/XCD.
    const int lin = blockIdx.x;
    const int wg = (lin & 7) * 64 + (lin >> 3);
    const int mb = (wg >> 5) * 256;   // M tile (16)
    const int nb = (wg & 31) * 128;   // N tile (32)

    // A staging: 256 rows x 64 bf16 = 8 x 256thr x 16B; chunk-XOR on source
    int offg[8], offl[8];
#pragma unroll
    for (int p = 0; p < 8; ++p) {
        int s = p * 256 + tid;
        int rl = s >> 3, pc = s & 7;
        int lc = pc ^ (rl & 7);
        offg[p] = rl * IN_F + lc * 8;
        offl[p] = s * 8;                 // lane-contiguous LDS dest
    }
    const u16* baseA = A + (size_t)mb * IN_F;

    // A fragment ds_read bases (bytes); imm = i*2048 (+8192 for rows 4-7)
    const u32 sAb = lds_addr(sA);
    const u32 aB0 = sAb + (u32)((wr * 128 + ln) * 128 + ((quad ^ lnx) * 16));
    const u32 aB1 = sAb + (u32)((wr * 128 + ln) * 128 + (((4 + quad) ^ lnx) * 16));

    // B global addresses: frag (j,kk): row = nb + wc*64 + j*16 + ln,
    // byte = row*8192 + ko*2 + (kk*4+quad)*16.  kk=1 -> offset:64 imm.
    // Advanced +128 B per K-tile.
    u64 bAddr[4];
#pragma unroll
    for (int j = 0; j < 4; ++j)
        bAddr[j] = (u64)(const char*)(B + (size_t)(nb + wc * 64 + j * 16 + ln) * IN_F)
                 + (u64)(quad * 16);

    // bias for this thread's 4 output column groups
    float bj[4];
#pragma unroll
    for (int j = 0; j < 4; ++j)
        bj[j] = bias[nb + wc * 64 + j * 16 + ln];

    f32x4 acc[8][4];
#pragma unroll
    for (int i = 0; i < 8; ++i)
#pragma unroll
        for (int j = 0; j < 4; ++j) acc[i][j] = (f32x4)0.0f;

    bf16x8 av[4][2];     // A fragments, 4 rows at a time (reused per batch)
    bf16x8 bv[4][2];     // B fragments, single-buffered (last use: MROW3)

#define DSR(dst, base, IMM) \
    asm volatile("ds_read_b128 %0, %1 offset:" #IMM \
                 : "=v"(dst) : "v"(base))

#define GLB0(dst, ap) \
    asm volatile("global_load_dwordx4 %0, %1, off" : "=v"(dst) : "v"(ap))
#define GLB1(dst, ap) \
    asm volatile("global_load_dwordx4 %0, %1, off offset:64" : "=v"(dst) : "v"(ap))

#define WVL(V, L) \
    asm volatile("s_waitcnt vmcnt(" #V ") lgkmcnt(" #L ")"); \
    __builtin_amdgcn_sched_barrier(0);
#define WV(V) \
    asm volatile("s_waitcnt vmcnt(" #V ")"); \
    __builtin_amdgcn_sched_barrier(0);
#define WL(L) \
    asm volatile("s_waitcnt lgkmcnt(" #L ")"); \
    __builtin_amdgcn_sched_barrier(0);

// col-block J x A-rows 0..3 (8 MFMA, same-acc dep distance 4)
#define MCOL(J) \
    acc[0][J] = __builtin_amdgcn_mfma_f32_16x16x32_bf16( \
        av[0][0], bv[J][0], acc[0][J], 0, 0, 0); \
    acc[1][J] = __builtin_amdgcn_mfma_f32_16x16x32_bf16( \
        av[1][0], bv[J][0], acc[1][J], 0, 0, 0); \
    acc[2][J] = __builtin_amdgcn_mfma_f32_16x16x32_bf16( \
        av[2][0], bv[J][0], acc[2][J], 0, 0, 0); \
    acc[3][J] = __builtin_amdgcn_mfma_f32_16x16x32_bf16( \
        av[3][0], bv[J][0], acc[3][J], 0, 0, 0); \
    acc[0][J] = __builtin_amdgcn_mfma_f32_16x16x32_bf16( \
        av[0][1], bv[J][1], acc[0][J], 0, 0, 0); \
    acc[1][J] = __builtin_amdgcn_mfma_f32_16x16x32_bf16( \
        av[1][1], bv[J][1], acc[1][J], 0, 0, 0); \
    acc[2][J] = __builtin_amdgcn_mfma_f32_16x16x32_bf16( \
        av[2][1], bv[J][1], acc[2][J], 0, 0, 0); \
    acc[3][J] = __builtin_amdgcn_mfma_f32_16x16x32_bf16( \
        av[3][1], bv[J][1], acc[3][J], 0, 0, 0);

// A-row IR x all col-blocks (8 MFMA, same-acc dep distance 4)
#define MROW(IR, ACR) \
    acc[ACR][0] = __builtin_amdgcn_mfma_f32_16x16x32_bf16( \
        av[IR][0], bv[0][0], acc[ACR][0], 0, 0, 0); \
    acc[ACR][1] = __builtin_amdgcn_mfma_f32_16x16x32_bf16( \
        av[IR][0], bv[1][0], acc[ACR][1], 0, 0, 0); \
    acc[ACR][2] = __builtin_amdgcn_mfma_f32_16x16x32_bf16( \
        av[IR][0], bv[2][0], acc[ACR][2], 0, 0, 0); \
    acc[ACR][3] = __builtin_amdgcn_mfma_f32_16x16x32_bf16( \
        av[IR][0], bv[3][0], acc[ACR][3], 0, 0, 0); \
    acc[ACR][0] = __builtin_amdgcn_mfma_f32_16x16x32_bf16( \
        av[IR][1], bv[0][1], acc[ACR][0], 0, 0, 0); \
    acc[ACR][1] = __builtin_amdgcn_mfma_f32_16x16x32_bf16( \
        av[IR][1], bv[1][1], acc[ACR][1], 0, 0, 0); \
    acc[ACR][2] = __builtin_amdgcn_mfma_f32_16x16x32_bf16( \
        av[IR][1], bv[2][1], acc[ACR][2], 0, 0, 0); \
    acc[ACR][3] = __builtin_amdgcn_mfma_f32_16x16x32_bf16( \
        av[IR][1], bv[3][1], acc[ACR][3], 0, 0, 0);

#define ISSUE_B() \
    GLB0(bv[0][0], bAddr[0]); GLB1(bv[0][1], bAddr[0]); \
    GLB0(bv[1][0], bAddr[1]); GLB1(bv[1][1], bAddr[1]); \
    GLB0(bv[2][0], bAddr[2]); GLB1(bv[2][1], bAddr[2]); \
    GLB0(bv[3][0], bAddr[3]); GLB1(bv[3][1], bAddr[3]);

    // ---- prologue: A(0) -> buf0, publish; issue B(0) ----
#pragma unroll
    for (int p = 0; p < 8; ++p)
        async_copy16(baseA + offg[p], &sA[offl[p]]);
    asm volatile("s_waitcnt vmcnt(0)");
    __builtin_amdgcn_s_barrier();
    ISSUE_B();                                   // 8 outstanding at loop entry
    __builtin_amdgcn_sched_barrier(0);

#pragma unroll 1
    for (int t = 0; t < 64; ++t) {
        const int cur = t & 1;
        const u32 curOff = (u32)cur << 15;       // cur * 32768 B
        const u32 aC0 = aB0 + curOff, aC1 = aB1 + curOff;
        u16* aNx = sA + (cur ^ 1) * TILE_A_E;
        const int ko1 = ((t + 1) & 63) << 6;

        // ---- A-DMA(t+1) -> buf^1 (8 VMEM ops; no LDS hazard vs buf cur) ----
#pragma unroll
        for (int p = 0; p < 8; ++p)
            async_copy16(baseA + offg[p] + ko1, &aNx[offl[p]]);
        __builtin_amdgcn_sched_barrier(0);

        // ---- batch 1: av rows 0-3; MCOL ladder on B(t) ----
        DSR(av[0][0], aC0, 0);     DSR(av[0][1], aC1, 0);
        DSR(av[1][0], aC0, 2048);  DSR(av[1][1], aC1, 2048);
        DSR(av[2][0], aC0, 4096);  DSR(av[2][1], aC1, 4096);
        DSR(av[3][0], aC0, 6144);  DSR(av[3][1], aC1, 6144);
        __builtin_amdgcn_s_setprio(1);
        WVL(14, 0); MCOL(0);
        WV(12);     MCOL(1);
        WV(10);     MCOL(2);
        WV(8);      MCOL(3);
        __builtin_amdgcn_sched_barrier(0);
        __builtin_amdgcn_s_setprio(0);

        // ---- batch 2: av rows 4-7; MROW lgkm ladder (bv reused in regs) ----
        DSR(av[0][0], aC0, 8192);   DSR(av[0][1], aC1, 8192);
        DSR(av[1][0], aC0, 10240);  DSR(av[1][1], aC1, 10240);
        DSR(av[2][0], aC0, 12288);  DSR(av[2][1], aC1, 12288);
        DSR(av[3][0], aC0, 14336);  DSR(av[3][1], aC1, 14336);
        __builtin_amdgcn_s_setprio(1);
        WL(6); MROW(0, 4);
        WL(4); MROW(1, 5);
        WL(2); MROW(2, 6);
        WL(0); MROW(3, 7);
        __builtin_amdgcn_sched_barrier(0);
        __builtin_amdgcn_s_setprio(0);

        // ---- B(t+1): bv regs dead after MROW3 issue; advance + load ----
#pragma unroll
        for (int j = 0; j < 4; ++j) bAddr[j] += 128;
        ISSUE_B();
        __builtin_amdgcn_sched_barrier(0);

        // ---- tile boundary: A-DMA(t+1) done, B(t+1) stays in flight ----
        WV(8);
        __builtin_amdgcn_s_barrier();
    }

#undef DSR
#undef GLB0
#undef GLB1
#undef WVL
#undef WV
#undef WL
#undef MCOL
#undef MROW
#undef ISSUE_B

    // drain trailing B/A prefetches before epilogue (bv VGPRs get reused)
    asm volatile("s_waitcnt vmcnt(0) lgkmcnt(0)");
    __builtin_amdgcn_sched_barrier(0);

    // ---- epilogue: C[row][col] = acc + bias[col]
#pragma unroll
    for (int i = 0; i < 8; ++i) {
        const int mrow = mb + wr * 128 + i * 16 + quad * 4;
#pragma unroll
        for (int j = 0; j < 4; ++j) {
            const int col = nb + wc * 64 + j * 16 + ln;
            float* cp = C + (size_t)mrow * OUT_F + col;
#pragma unroll
            for (int r = 0; r < 4; ++r)
                cp[(size_t)r * OUT_F] = acc[i][j][r] + bj[j];
        }
    }
}

extern "C" void kernel_launch(void* const* d_in, const int* in_sizes, int n_in,
                              void* d_out, int out_size, void* d_ws, size_t ws_size,
                              hipStream_t stream) {
    const float* x = (const float*)d_in[0];       // [2,2048,4096] fp32
    const int* wq = (const int*)d_in[1];          // [NUM_GROUPS*12]
    const float* wn = (const float*)d_in[2];      // [NUM_GROUPS]
    const float* bias = (const float*)d_in[3];    // [4096]
    float* out = (float*)d_out;                   // [2,2048,4096] fp32

    u16* Wb = (u16*)d_ws;                         // 32 MB
    u16* Xb = Wb + (size_t)OUT_F * IN_F;          // 32 MB

    prep_kernel<<<16384, 256, 0, stream>>>(x, wq, wn, Wb, Xb);
    gemm_bt_kernel<<<512, 256, 0, stream>>>(Xb, Wb, bias, out);
}

// Round 10
// 141.795 us; speedup vs baseline: 1.3789x; 1.3789x over previous
//
#include <hip/hip_runtime.h>

typedef unsigned short u16;
typedef unsigned int u32;

typedef __bf16 bf16x8 __attribute__((ext_vector_type(8)));
typedef float f32x4 __attribute__((ext_vector_type(4)));

#define OUT_F 4096
#define IN_F 4096
#define M_ROWS 4096              // 2 * 2048
#define NUM_GROUPS ((OUT_F * IN_F) / 32)   // 524288

// ---------- helpers ----------

__device__ __forceinline__ u16 f2bf(float f) {
    union { float f; u32 u; } c; c.f = f;
    u32 u = c.u;
    u += 0x7fffu + ((u >> 16) & 1u);   // round-to-nearest-even (finite inputs)
    return (u16)(u >> 16);
}

__device__ __forceinline__ u32 pk2(float a, float b) {
    return (u32)f2bf(a) | ((u32)f2bf(b) << 16);
}

// async global -> LDS, 16 bytes per lane (global_load_lds_dwordx4)
__device__ __forceinline__ void async_copy16(const u16* g, u16* l) {
    __builtin_amdgcn_global_load_lds(
        (const __attribute__((address_space(1))) u32*)g,
        (__attribute__((address_space(3))) u32*)l,
        16, 0, 0);
}

// 32-bit LDS byte address for inline-asm ds_read
__device__ __forceinline__ u32 lds_addr(const u16* p) {
    return (u32)(uintptr_t)(const __attribute__((address_space(3))) u16*)p;
}

// ---------- fused prep (unchanged — not the bottleneck) ----------
__global__ __launch_bounds__(256) void prep_kernel(
        const float* __restrict__ x, const int* __restrict__ q,
        const float* __restrict__ scales,
        u16* __restrict__ W, u16* __restrict__ Xb) {
    int bid = blockIdx.x;
    int tid = threadIdx.x;
    if (bid < 8192) {
        int t = bid * 256 + tid;                 // [0, NUM_TRIPLETS)
        int b0 = q[3 * t];
        int b1 = q[3 * t + 1];
        int b2 = q[3 * t + 2];
        float mv = scales[t >> 2];
        float s = mv * (2.0f / 7.0f);            // w = v*s - mv
        float o = -mv;

        int v0 = b0 & 7;
        int v1 = (b0 >> 3) & 7;
        int v2 = ((b0 >> 6) & 3) | ((b1 & 1) << 2);
        int v3 = (b1 >> 1) & 7;
        int v4 = (b1 >> 4) & 7;
        int v5 = ((b1 >> 7) & 1) | ((b2 & 3) << 1);
        int v6 = (b2 >> 2) & 7;
        int v7 = (b2 >> 5) & 7;
        uint4 w;
        w.x = pk2(fmaf((float)v0, s, o), fmaf((float)v1, s, o));
        w.y = pk2(fmaf((float)v2, s, o), fmaf((float)v3, s, o));
        w.z = pk2(fmaf((float)v4, s, o), fmaf((float)v5, s, o));
        w.w = pk2(fmaf((float)v6, s, o), fmaf((float)v7, s, o));
        ((uint4*)W)[t] = w;
    } else {
        int i = (bid - 8192) * 256 + tid;
        const float4* p = (const float4*)x + (size_t)i * 2;
        float4 u = p[0], v = p[1];
        uint4 w;
        w.x = pk2(u.x, u.y);
        w.y = pk2(u.z, u.w);
        w.z = pk2(v.x, v.y);
        w.w = pk2(v.z, v.w);
        ((uint4*)Xb)[i] = w;
    }
}

// ---------- 256x128 tile, 2 blocks/CU, single-buffer bf16 GEMM ----------
// C[m][n] = sum_k A[m][k]*B[n][k] + bias[n]
//
// R10: R8 base (best so far, 116.6us) with ONE mechanism changed — break the
// in-phase lock between the two co-resident blocks:
//  (1) setprio REMOVED: prio-1 MFMA waves starved the sibling block's prio-0
//      ds_read issue on the shared SIMDs -> port idled under every MFMA burst
//      and the blocks were dragged into phase (MfmaUtil 51% + port 53% ~=
//      temporally exclusive, across R5/R8 alike).
//  (2) deliberate dephase: one block of each co-resident pair sleeps ~2176cyc
//      (half a tile period) once after the prologue, so its port bursts land
//      under the sibling's MFMA bursts. Pair parity (lin^(lin>>8))&1 covers
//      both plausible block->CU mappings. In-phase lock is stable (shared-
//      resource slowdown is symmetric); anti-phase must be seeded.
// Everything else byte-identical to R8.
__global__ __launch_bounds__(256, 2) void gemm_bt_kernel(
        const u16* __restrict__ A, const u16* __restrict__ B,
        const float* __restrict__ bias, float* __restrict__ C) {
    __shared__ u16 sA[256 * 64];    // 32 KB
    __shared__ u16 sB[128 * 64];    // 16 KB

    const int tid = threadIdx.x;
    const int lane = tid & 63;
    const int w = tid >> 6;          // wave 0..3
    const int wr = w >> 1;           // wave row 0..1 (rows wr*128 + [0,128))
    const int wc = w & 1;            // wave col 0..1 (cols wc*64 + [0,64))
    const int ln = lane & 15;
    const int quad = lane >> 4;
    const int lnx = ln & 7;

    // XCD-aware bijective swizzle: 512 blocks, 8 XCDs, 64 contiguous/XCD.
    const int lin = blockIdx.x;
    const int wg = (lin & 7) * 64 + (lin >> 3);
    const int mb = (wg >> 5) * 256;   // M tile (16)
    const int nb = (wg & 31) * 128;   // N tile (32)

    // staging geometry: slot s = p*256+tid; row = s>>3, phys chunk = s&7,
    // logical chunk = pc ^ (row&7) (XOR swizzle on the global source).
    int offg[8], offl[8];
#pragma unroll
    for (int p = 0; p < 8; ++p) {
        int s = p * 256 + tid;
        int rl = s >> 3, pc = s & 7;
        int lc = pc ^ (rl & 7);
        offg[p] = rl * IN_F + lc * 8;
        offl[p] = s * 8;                 // lane-contiguous LDS dest
    }
    const u16* baseA = A + (size_t)mb * IN_F;
    const u16* baseB = B + (size_t)nb * IN_F;

    // fragment read bases (bytes). Row stride 128 B.
    const u32 sAb = lds_addr(sA);
    const u32 sBb = lds_addr(sB);
    const u32 aB0 = sAb + (u32)((wr * 128 + ln) * 128 + ((quad ^ lnx) * 16));
    const u32 aB1 = sAb + (u32)((wr * 128 + ln) * 128 + (((4 + quad) ^ lnx) * 16));
    const u32 bB0 = sBb + (u32)((wc * 64 + ln) * 128 + ((quad ^ lnx) * 16));
    const u32 bB1 = sBb + (u32)((wc * 64 + ln) * 128 + (((4 + quad) ^ lnx) * 16));

    // bias for this thread's 4 output column groups
    float bj[4];
#pragma unroll
    for (int j = 0; j < 4; ++j)
        bj[j] = bias[nb + wc * 64 + j * 16 + ln];

    f32x4 acc[8][4];
#pragma unroll
    for (int i = 0; i < 8; ++i)
#pragma unroll
        for (int j = 0; j < 4; ++j) acc[i][j] = (f32x4)0.0f;

    bf16x8 av[4][2];     // A fragments, 4 rows at a time (reused per batch)
    bf16x8 bv[4][2];     // B fragments, live whole tile

#define DSR(dst, base, IMM) \
    asm volatile("ds_read_b128 %0, %1 offset:" #IMM \
                 : "=v"(dst) : "v"(base))

#define WAITG(N) \
    asm volatile("s_waitcnt lgkmcnt(" #N ")"); \
    __builtin_amdgcn_sched_barrier(0);

// one A-row fragment x all 4 B-frags x 2 kk; same-acc ops are 4 apart
#define MROW(IR, ACR) \
    acc[ACR][0] = __builtin_amdgcn_mfma_f32_16x16x32_bf16( \
        av[IR][0], bv[0][0], acc[ACR][0], 0, 0, 0); \
    acc[ACR][1] = __builtin_amdgcn_mfma_f32_16x16x32_bf16( \
        av[IR][0], bv[1][0], acc[ACR][1], 0, 0, 0); \
    acc[ACR][2] = __builtin_amdgcn_mfma_f32_16x16x32_bf16( \
        av[IR][0], bv[2][0], acc[ACR][2], 0, 0, 0); \
    acc[ACR][3] = __builtin_amdgcn_mfma_f32_16x16x32_bf16( \
        av[IR][0], bv[3][0], acc[ACR][3], 0, 0, 0); \
    acc[ACR][0] = __builtin_amdgcn_mfma_f32_16x16x32_bf16( \
        av[IR][1], bv[0][1], acc[ACR][0], 0, 0, 0); \
    acc[ACR][1] = __builtin_amdgcn_mfma_f32_16x16x32_bf16( \
        av[IR][1], bv[1][1], acc[ACR][1], 0, 0, 0); \
    acc[ACR][2] = __builtin_amdgcn_mfma_f32_16x16x32_bf16( \
        av[IR][1], bv[2][1], acc[ACR][2], 0, 0, 0); \
    acc[ACR][3] = __builtin_amdgcn_mfma_f32_16x16x32_bf16( \
        av[IR][1], bv[3][1], acc[ACR][3], 0, 0, 0);

    // ---- prologue: stage tile 0, drain, publish ----
#pragma unroll
    for (int p = 0; p < 8; ++p)
        async_copy16(baseA + offg[p], &sA[offl[p]]);
#pragma unroll
    for (int p = 0; p < 4; ++p)
        async_copy16(baseB + offg[p], &sB[offl[p]]);
    asm volatile("s_waitcnt vmcnt(0)");
    __builtin_amdgcn_s_barrier();

    // ---- dephase: half of each co-resident pair starts ~2176 cyc late ----
    if ((lin ^ (lin >> 8)) & 1) {
        asm volatile("s_sleep 34");
    }

#pragma unroll 1
    for (int t = 0; t < 64; ++t) {
        // ---- batch 1: B(8) + A rows 0..3 (8 reads) ----
        DSR(bv[0][0], bB0, 0);     DSR(bv[0][1], bB1, 0);
        DSR(bv[1][0], bB0, 2048);  DSR(bv[1][1], bB1, 2048);
        DSR(bv[2][0], bB0, 4096);  DSR(bv[2][1], bB1, 4096);
        DSR(bv[3][0], bB0, 6144);  DSR(bv[3][1], bB1, 6144);
        DSR(av[0][0], aB0, 0);     DSR(av[0][1], aB1, 0);
        DSR(av[1][0], aB0, 2048);  DSR(av[1][1], aB1, 2048);
        DSR(av[2][0], aB0, 4096);  DSR(av[2][1], aB1, 4096);
        DSR(av[3][0], aB0, 6144);  DSR(av[3][1], aB1, 6144);
        WAITG(6); MROW(0, 0);
        WAITG(4); MROW(1, 1);
        WAITG(2); MROW(2, 2);
        WAITG(0); MROW(3, 3);

        // ---- batch 2: A rows 4..7 (registers reused; WAR safe in-order) ----
        DSR(av[0][0], aB0, 8192);   DSR(av[0][1], aB1, 8192);
        DSR(av[1][0], aB0, 10240);  DSR(av[1][1], aB1, 10240);
        DSR(av[2][0], aB0, 12288);  DSR(av[2][1], aB1, 12288);
        DSR(av[3][0], aB0, 14336);  DSR(av[3][1], aB1, 14336);
        WAITG(6); MROW(0, 4);
        WAITG(4); MROW(1, 5);
        WAITG(2); MROW(2, 6);
        WAITG(0); MROW(3, 7);

        // ---- all reads of tile t complete; restage buffer ----
        __builtin_amdgcn_s_barrier();
        if (t < 63) {
            const int ko1 = (t + 1) << 6;
#pragma unroll
            for (int p = 0; p < 8; ++p)
                async_copy16(baseA + offg[p] + ko1, &sA[offl[p]]);
#pragma unroll
            for (int p = 0; p < 4; ++p)
                async_copy16(baseB + offg[p] + ko1, &sB[offl[p]]);
        }
        asm volatile("s_waitcnt vmcnt(0)");
        __builtin_amdgcn_s_barrier();
    }

#undef DSR
#undef WAITG
#undef MROW

    // ---- epilogue: C[row][col] = acc + bias[col]
#pragma unroll
    for (int i = 0; i < 8; ++i) {
        const int mrow = mb + wr * 128 + i * 16 + quad * 4;
#pragma unroll
        for (int j = 0; j < 4; ++j) {
            const int col = nb + wc * 64 + j * 16 + ln;
            float* cp = C + (size_t)mrow * OUT_F + col;
#pragma unroll
            for (int r = 0; r < 4; ++r)
                cp[(size_t)r * OUT_F] = acc[i][j][r] + bj[j];
        }
    }
}

extern "C" void kernel_launch(void* const* d_in, const int* in_sizes, int n_in,
                              void* d_out, int out_size, void* d_ws, size_t ws_size,
                              hipStream_t stream) {
    const float* x = (const float*)d_in[0];       // [2,2048,4096] fp32
    const int* wq = (const int*)d_in[1];          // [NUM_GROUPS*12]
    const float* wn = (const float*)d_in[2];      // [NUM_GROUPS]
    const float* bias = (const float*)d_in[3];    // [4096]
    float* out = (float*)d_out;                   // [2,2048,4096] fp32

    u16* Wb = (u16*)d_ws;                         // 32 MB
    u16* Xb = Wb + (size_t)OUT_F * IN_F;          // 32 MB

    prep_kernel<<<16384, 256, 0, stream>>>(x, wq, wn, Wb, Xb);
    gemm_bt_kernel<<<512, 256, 0, stream>>>(Xb, Wb, bias, out);
}